// Round 2
// baseline (90.541 us; speedup 1.0000x reference)
//
#include <hip/hip_runtime.h>

// LIF layer: input (T=256, B=32, N=4096) fp32. Recurrence over T; B*N columns
// independent. Outputs concatenated: spikes[T][B*N] (0/1 f32), volts[T][B*N].
//
// R1 structure: one SCALAR column per thread -> 131072 threads = 2048 waves
// = 8 waves/CU (all 4 SIMDs active), vs R0's float4 columns (2 waves/CU,
// latency-parallelism limited at 4.9 TB/s). Coalescing unchanged: wave64
// scalar loads = 256 B contiguous. unroll 16 keeps 16 loads in flight per
// thread; nontemporal hints on all three touch-once streams.

#define T_STEPS 256
#define BN      (32 * 4096)      // 131072 columns

__global__ __launch_bounds__(256) void lif_kernel(
    const float* __restrict__ in,
    float* __restrict__ out,
    const float* __restrict__ decay_p,
    const float* __restrict__ vth_p,
    const float* __restrict__ vreset_p)
{
    const int col = blockIdx.x * 256 + threadIdx.x;   // 0..BN-1

    const float decay   = *decay_p;
    const float v_th    = *vth_p;
    const float v_reset = *vreset_p;

    const float* __restrict__ ip = in + col;
    float*       __restrict__ sp = out + col;                           // spikes
    float*       __restrict__ vp = out + (size_t)T_STEPS * BN + col;    // volts

    float v = 0.f;

    #pragma unroll 16
    for (int t = 0; t < T_STEPS; ++t) {
        float I = __builtin_nontemporal_load(ip);  ip += BN;
        // decay*V + I with SEPARATE mul/add roundings (match numpy; no FMA).
        float n = __fadd_rn(__fmul_rn(decay, v), I);
        bool spk = (n >= v_th);
        v = spk ? v_reset : n;
        __builtin_nontemporal_store(spk ? 1.f : 0.f, sp);  sp += BN;
        __builtin_nontemporal_store(v, vp);                vp += BN;
    }
}

extern "C" void kernel_launch(void* const* d_in, const int* in_sizes, int n_in,
                              void* d_out, int out_size, void* d_ws, size_t ws_size,
                              hipStream_t stream) {
    const float* in      = (const float*)d_in[0];
    const float* decay_p = (const float*)d_in[1];
    const float* vth_p   = (const float*)d_in[2];
    const float* vrst_p  = (const float*)d_in[3];
    float*       out     = (float*)d_out;

    dim3 grid(BN / 256);   // 512 blocks
    dim3 block(256);
    hipLaunchKernelGGL(lif_kernel, grid, block, 0, stream,
                       in, out, decay_p, vth_p, vrst_p);
}